// Round 3
// baseline (262.743 us; speedup 1.0000x reference)
//
#include <hip/hip_runtime.h>
#include <math.h>

#define M_ 4
#define A_ 256
#define RBF_ 64
#define F_ 32
#define H_ 32
#define SI_ 32
#define TF_ 128   // 4 tags * F

typedef __attribute__((ext_vector_type(8))) short bf16x8;
typedef __attribute__((ext_vector_type(4))) float f32x4;
typedef __attribute__((ext_vector_type(8))) unsigned short us8;

__device__ __forceinline__ unsigned short f2bf(float f) {
  union { float f; unsigned u; } v; v.f = f;
  unsigned r = v.u + 0x7FFFu + ((v.u >> 16) & 1u);   // RNE bf16
  return (unsigned short)(r >> 16);
}

__device__ __forceinline__ float sspf(float x) {
  // log(0.5*exp(x)+0.5) = softplus(x) - ln2, numerically stable
  return fmaxf(x, 0.f) + log1pf(expf(-fabsf(x))) - 0.6931471805599453f;
}

// ---------------------------------------------------------------------------
// Setup: collapse the two linear Dense layers per tag into one 64x32 map.
// ws layout: WcT bf16 [tf=128][k=64] (16384 B), then bc fp32 [128] at +16384.
// tf = tag*32 + f, tag order {00,01,10,11}.
// ---------------------------------------------------------------------------
__global__ __launch_bounds__(256) void combine_weights(
    const float* __restrict__ w1_00, const float* __restrict__ b1_00,
    const float* __restrict__ w2_00, const float* __restrict__ b2_00,
    const float* __restrict__ w1_01, const float* __restrict__ b1_01,
    const float* __restrict__ w2_01, const float* __restrict__ b2_01,
    const float* __restrict__ w1_10, const float* __restrict__ b1_10,
    const float* __restrict__ w2_10, const float* __restrict__ b2_10,
    const float* __restrict__ w1_11, const float* __restrict__ b1_11,
    const float* __restrict__ w2_11, const float* __restrict__ b2_11,
    unsigned short* __restrict__ wsT, float* __restrict__ bcw)
{
  const float* w1s[4] = {w1_00, w1_01, w1_10, w1_11};
  const float* b1s[4] = {b1_00, b1_01, b1_10, b1_11};
  const float* w2s[4] = {w2_00, w2_01, w2_10, w2_11};
  const float* b2s[4] = {b2_00, b2_01, b2_10, b2_11};
  int tid = blockIdx.x * 256 + threadIdx.x;    // 0..8191
  int k   = tid >> 7;
  int tf  = tid & 127;
  int tag = tf >> 5, f = tf & 31;
  const float* w1 = w1s[tag];
  const float* w2 = w2s[tag];
  float s = 0.f;
  for (int h = 0; h < H_; ++h) s += w1[k * H_ + h] * w2[h * F_ + f];
  wsT[tf * 64 + k] = f2bf(s);                  // transposed for B-frag loads
  if (tid < TF_) {
    const float* b1 = b1s[tag];
    const float* b2 = b2s[tag];
    float sb = b2[f];
    for (int h = 0; h < H_; ++h) sb += b1[h] * w2[h * F_ + f];
    bcw[tf] = sb;                              // bias stays fp32
  }
}

// ---------------------------------------------------------------------------
// Main fused kernel: one block per (m,a), 4 waves.
//  GEMM R[b,tf] = image[m,a,b,:]@Wc + bc via mfma_f32_16x16x32_bf16.
//  Tiles: 16 b-tiles x 8 tf-tiles; wave w owns b-tiles {w,4+w} per 128-b chunk.
//  C-frag layout (verified): row(b) = quad*4+reg, col(tf) = lane&15.
//  Contraction with feat0/feat1/vectors fused on the C-frags; 22 fp32
//  partials/lane; 16-copy LDS reduce (quad x wave); SI + activation epilogue.
// LDS: sB 128x72 bf16 (18432) | sBc 128 f32 (512) | sA 128x72 bf16 (18432)
//      red[352*17] f32 (23936) aliases the whole region after compute.
// Total 37376 B -> 4 blocks/CU; grid 1024 blocks fully co-resident.
// ---------------------------------------------------------------------------
#define SB_ROW 72
#define SA_ROW 72

__global__ __launch_bounds__(256, 4) void conv_main(
    const float* __restrict__ image, const float* __restrict__ vectors,
    const float* __restrict__ feat0, const float* __restrict__ feat1,
    const unsigned short* __restrict__ wsT, const float* __restrict__ bcw,
    const float* __restrict__ w_si0, const float* __restrict__ w_si1,
    const float* __restrict__ b_act0, const float* __restrict__ b_act1,
    float* __restrict__ out)
{
  __shared__ __align__(16) char smem[37376];
  unsigned short* sB  = (unsigned short*)smem;            // [128][72] bf16
  float*          sBc = (float*)(smem + 18432);           // [128] f32
  unsigned short* sA  = (unsigned short*)(smem + 18944);  // [128][72] bf16
  float*          red = (float*)smem;                     // [352][17] alias

  const int t    = threadIdx.x;
  const int m    = blockIdx.x >> 8;
  const int a    = blockIdx.x & 255;
  const int w    = t >> 6;
  const int l    = t & 63;
  const int n    = l & 15;        // tile col (tf within tile), also A/B row sel
  const int quad = l >> 4;        // k-group for frags; b-subgroup for C

  // ---- stage WcT (bf16) + bias to LDS ----
  // 128 rows x 64 bf16 = 8192 shorts = 1024 groups of 8 -> 4 iters x 256 thr
  #pragma unroll
  for (int i = 0; i < 4; ++i) {
    int g = t + 256 * i;          // 0..1023 groups of 8 bf16
    int tf = g >> 3, c8 = g & 7;
    *(us8*)&sB[tf * SB_ROW + c8 * 8] = *(const us8*)&wsT[tf * 64 + c8 * 8];
  }
  if (t < 128) sBc[t] = bcw[t];

  // contraction partials
  float p000[2], p110[2], p011[6], p101[6], p111[6];
  #pragma unroll
  for (int i = 0; i < 2; ++i) { p000[i] = 0.f; p110[i] = 0.f; }
  #pragma unroll
  for (int i = 0; i < 6; ++i) { p011[i] = 0.f; p101[i] = 0.f; p111[i] = 0.f; }

  const float* imgMA = image + ((size_t)(m * A_ + a)) * A_ * RBF_;
  const float* vecMA = vectors + ((size_t)(m * A_ + a)) * A_ * 3;

  #pragma unroll 1
  for (int c = 0; c < 2; ++c) {
    if (c) __syncthreads();       // chunk-0 readers done before restage
    // ---- stage image chunk (128 b-rows) as bf16 ----
    const float* base = imgMA + (size_t)c * 128 * RBF_;
    #pragma unroll
    for (int i = 0; i < 4; ++i) {
      int g = t + 256 * i;        // 0..1023 groups of 8 floats
      int r = g >> 3, c8 = g & 7;
      const float* src = base + r * RBF_ + c8 * 8;
      float4 v0 = *(const float4*)(src);
      float4 v1 = *(const float4*)(src + 4);
      us8 pk;
      pk[0] = f2bf(v0.x); pk[1] = f2bf(v0.y); pk[2] = f2bf(v0.z); pk[3] = f2bf(v0.w);
      pk[4] = f2bf(v1.x); pk[5] = f2bf(v1.y); pk[6] = f2bf(v1.z); pk[7] = f2bf(v1.w);
      *(us8*)&sA[r * SA_ROW + c8 * 8] = pk;
    }
    __syncthreads();

    // ---- 2 b-tiles per wave per chunk ----
    #pragma unroll 1
    for (int bti = 0; bti < 2; ++bti) {
      const int btl  = w + 4 * bti;          // 0..7 local b-tile
      const int brow = btl * 16;             // local row base in sA
      const int bg   = c * 128 + brow + quad * 4;  // global b for r=0

      // A-frags for this b-tile (reused across all 8 tf-tiles)
      const bf16x8 a0 = *(const bf16x8*)&sA[(brow + n) * SA_ROW + quad * 8];
      const bf16x8 a1 = *(const bf16x8*)&sA[(brow + n) * SA_ROW + 32 + quad * 8];

      // vectors for this lane's 4 b's
      const float* vp = vecMA + (size_t)bg * 3;
      float vx[4], vy[4], vz[4];
      #pragma unroll
      for (int r = 0; r < 4; ++r) {
        vx[r] = vp[r * 3 + 0]; vy[r] = vp[r * 3 + 1]; vz[r] = vp[r * 3 + 2];
      }

      #pragma unroll
      for (int ct = 0; ct < 8; ++ct) {
        const bf16x8 b0 = *(const bf16x8*)&sB[(ct * 16 + n) * SB_ROW + quad * 8];
        const bf16x8 b1 = *(const bf16x8*)&sB[(ct * 16 + n) * SB_ROW + 32 + quad * 8];
        const float bcv = sBc[ct * 16 + n];
        f32x4 acc = {bcv, bcv, bcv, bcv};
        acc = __builtin_amdgcn_mfma_f32_16x16x32_bf16(a0, b0, acc, 0, 0, 0);
        acc = __builtin_amdgcn_mfma_f32_16x16x32_bf16(a1, b1, acc, 0, 0, 0);

        const int which = ct & 1;
        const int f = which * 16 + n;        // feature within tag
        // per-r feature base index: (m*A + b)*F + f
        const int fb = (m * A_ + bg) * F_ + f;   // r advances by F_

        if (ct < 2) {            // tag 00 -> out_0x0_0
          #pragma unroll
          for (int r = 0; r < 4; ++r)
            p000[which] += acc[r] * feat0[fb + r * F_];
        } else if (ct < 4) {     // tag 01 -> out_0x1_1 = v * (R*feat0)
          #pragma unroll
          for (int r = 0; r < 4; ++r) {
            float s = acc[r] * feat0[fb + r * F_];
            p011[which * 3 + 0] += vx[r] * s;
            p011[which * 3 + 1] += vy[r] * s;
            p011[which * 3 + 2] += vz[r] * s;
          }
        } else if (ct < 6) {     // tag 10 -> out_1x0_1 = R * feat1
          #pragma unroll
          for (int r = 0; r < 4; ++r) {
            const float* fp = feat1 + (size_t)(fb + r * F_) * 3;
            p101[which * 3 + 0] += acc[r] * fp[0];
            p101[which * 3 + 1] += acc[r] * fp[1];
            p101[which * 3 + 2] += acc[r] * fp[2];
          }
        } else {                 // tag 11 -> out_1x1_0 (dot), out_1x1_1 (cross)
          #pragma unroll
          for (int r = 0; r < 4; ++r) {
            const float* fp = feat1 + (size_t)(fb + r * F_) * 3;
            float g0 = fp[0], g1 = fp[1], g2 = fp[2];
            float Rr = acc[r];
            p110[which] += Rr * (vx[r] * g0 + vy[r] * g1 + vz[r] * g2);
            p111[which * 3 + 0] += Rr * (vy[r] * g2 - vz[r] * g1);
            p111[which * 3 + 1] += Rr * (vz[r] * g0 - vx[r] * g2);
            p111[which * 3 + 2] += Rr * (vx[r] * g1 - vy[r] * g0);
          }
        }
      }
    }
    __syncthreads();   // all compute on this chunk done (before restage/red)
  }

  // ---- write 16-copy partials (red aliases sB/sBc/sA; all consumed) ----
  const int idx16 = w * 4 + quad;
  // slots: out000: f (0..31) | out110: 32+f | out011: 64+f*3+d
  //        out101: 160+f*3+d | out111: 256+f*3+d       (total 352)
  #pragma unroll
  for (int which = 0; which < 2; ++which) {
    int f = which * 16 + n;
    red[f * 17 + idx16]        = p000[which];
    red[(32 + f) * 17 + idx16] = p110[which];
    #pragma unroll
    for (int d = 0; d < 3; ++d) {
      red[(64 + f * 3 + d) * 17 + idx16]  = p011[which * 3 + d];
      red[(160 + f * 3 + d) * 17 + idx16] = p101[which * 3 + d];
      red[(256 + f * 3 + d) * 17 + idx16] = p111[which * 3 + d];
    }
  }
  __syncthreads();

  // ---- reduce 16 copies; result in column 16 ----
  for (int s = t; s < 352; s += 256) {
    float sm = 0.f;
    #pragma unroll
    for (int j = 0; j < 16; ++j) sm += red[s * 17 + j];
    red[s * 17 + 16] = sm;
  }
  __syncthreads();

  // ---- self-interaction + equivariant activation epilogue ----
  // cat0[i] = red[i*17+16] (i<64: out000|out110)
  // cat1[i] = red[(64+i)*17+16] (i<288: out011|out101|out111, (row,d) packed)
  const int outBase = (m * A_ + a) * SI_;
  if (t < 32) {
    const float* wr = w_si0 + t * 64;
    float s = 0.f;
    #pragma unroll 8
    for (int f = 0; f < 64; ++f) s += red[f * 17 + 16] * wr[f];
    s += b_act0[t];
    out[outBase + t] = sspf(s);
  } else if (t >= 64 && t < 96) {
    int g = t - 64;
    const float* wr = w_si1 + g * 96;
    float s0 = 0.f, s1 = 0.f, s2 = 0.f;
    #pragma unroll 8
    for (int f = 0; f < 96; ++f) {
      float wv = wr[f];
      s0 += red[(64 + f * 3 + 0) * 17 + 16] * wv;
      s1 += red[(64 + f * 3 + 1) * 17 + 16] * wv;
      s2 += red[(64 + f * 3 + 2) * 17 + 16] * wv;
    }
    float n2 = s0 * s0 + s1 * s1 + s2 * s2;
    float n1 = sqrtf(fmaxf(n2, 1e-7f));     // norm_with_epsilon, EPS=1e-7
    float a1 = sspf(n1 + b_act1[g]);
    float sc = a1 / n1;
    int ob = M_ * A_ * SI_ + (outBase + g) * 3;   // o0 is 32768 floats
    out[ob + 0] = s0 * sc;
    out[ob + 1] = s1 * sc;
    out[ob + 2] = s2 * sc;
  }
}

extern "C" void kernel_launch(void* const* d_in, const int* in_sizes, int n_in,
                              void* d_out, int out_size, void* d_ws, size_t ws_size,
                              hipStream_t stream) {
  const float* image   = (const float*)d_in[0];
  const float* vectors = (const float*)d_in[1];
  const float* feat0   = (const float*)d_in[2];
  const float* feat1   = (const float*)d_in[3];
  const float* w_si0   = (const float*)d_in[20];
  const float* w_si1   = (const float*)d_in[21];
  const float* b_act0  = (const float*)d_in[22];
  const float* b_act1  = (const float*)d_in[23];
  unsigned short* wsT = (unsigned short*)d_ws;           // 128*64 bf16 = 16384 B
  float* bcw = (float*)((char*)d_ws + 16384);            // 128 f32
  float* out = (float*)d_out;

  combine_weights<<<32, 256, 0, stream>>>(
      (const float*)d_in[4],  (const float*)d_in[5],
      (const float*)d_in[6],  (const float*)d_in[7],
      (const float*)d_in[8],  (const float*)d_in[9],
      (const float*)d_in[10], (const float*)d_in[11],
      (const float*)d_in[12], (const float*)d_in[13],
      (const float*)d_in[14], (const float*)d_in[15],
      (const float*)d_in[16], (const float*)d_in[17],
      (const float*)d_in[18], (const float*)d_in[19],
      wsT, bcw);

  conv_main<<<M_ * A_, 256, 0, stream>>>(
      image, vectors, feat0, feat1, wsT, bcw,
      w_si0, w_si1, b_act0, b_act1, out);
}

// Round 4
// 168.074 us; speedup vs baseline: 1.5633x; 1.5633x over previous
//
#include <hip/hip_runtime.h>
#include <math.h>

#define M_ 4
#define A_ 256
#define RBF_ 64
#define F_ 32
#define H_ 32
#define SI_ 32
#define TF_ 128   // 4 tags * F

typedef __attribute__((ext_vector_type(8))) short bf16x8;
typedef __attribute__((ext_vector_type(4))) float f32x4;
typedef __attribute__((ext_vector_type(8))) unsigned short us8;

__device__ __forceinline__ unsigned short f2bf(float f) {
  union { float f; unsigned u; } v; v.f = f;
  unsigned r = v.u + 0x7FFFu + ((v.u >> 16) & 1u);   // RNE bf16
  return (unsigned short)(r >> 16);
}

__device__ __forceinline__ float sspf(float x) {
  // log(0.5*exp(x)+0.5) = softplus(x) - ln2, numerically stable
  return fmaxf(x, 0.f) + log1pf(expf(-fabsf(x))) - 0.6931471805599453f;
}

// ---------------------------------------------------------------------------
// Setup: collapse the two linear Dense layers per tag into one 64x32 map.
// ws layout: WcT bf16 [tf=128][k=64] (16384 B), then bc fp32 [128] at +16384.
// tf = tag*32 + f, tag order {00,01,10,11}.
// ---------------------------------------------------------------------------
__global__ __launch_bounds__(256) void combine_weights(
    const float* __restrict__ w1_00, const float* __restrict__ b1_00,
    const float* __restrict__ w2_00, const float* __restrict__ b2_00,
    const float* __restrict__ w1_01, const float* __restrict__ b1_01,
    const float* __restrict__ w2_01, const float* __restrict__ b2_01,
    const float* __restrict__ w1_10, const float* __restrict__ b1_10,
    const float* __restrict__ w2_10, const float* __restrict__ b2_10,
    const float* __restrict__ w1_11, const float* __restrict__ b1_11,
    const float* __restrict__ w2_11, const float* __restrict__ b2_11,
    unsigned short* __restrict__ wsT, float* __restrict__ bcw)
{
  const float* w1s[4] = {w1_00, w1_01, w1_10, w1_11};
  const float* b1s[4] = {b1_00, b1_01, b1_10, b1_11};
  const float* w2s[4] = {w2_00, w2_01, w2_10, w2_11};
  const float* b2s[4] = {b2_00, b2_01, b2_10, b2_11};
  int tid = blockIdx.x * 256 + threadIdx.x;    // 0..8191
  int k   = tid >> 7;
  int tf  = tid & 127;
  int tag = tf >> 5, f = tf & 31;
  const float* w1 = w1s[tag];
  const float* w2 = w2s[tag];
  float s = 0.f;
  for (int h = 0; h < H_; ++h) s += w1[k * H_ + h] * w2[h * F_ + f];
  wsT[tf * 64 + k] = f2bf(s);                  // transposed for B-frag loads
  if (tid < TF_) {
    const float* b1 = b1s[tag];
    const float* b2 = b2s[tag];
    float sb = b2[f];
    for (int h = 0; h < H_; ++h) sb += b1[h] * w2[h * F_ + f];
    bcw[tf] = sb;                              // bias stays fp32
  }
}

// ---------------------------------------------------------------------------
// Main fused kernel: one block per (m,a), 4 waves.
//  GEMM R[b,tf] = image[m,a,b,:]@Wc + bc via mfma_f32_16x16x32_bf16.
//  Wave w owns b-tiles {w,4+w} per 128-b chunk. C-frag: row(b)=quad*4+reg,
//  col(tf)=lane&15.
//  Inner loops: which (unrolled x2, shares feat loads) outer, tag
//  (#pragma unroll 1 -- keeps one B-frag pair + one acc live at a time,
//  VGPR <= 128 so no scratch spill at 4 blocks/CU) inner.
// LDS: sB 128x72 bf16 (18432) | sBc 128 f32 (512) | sA 128x72 bf16 (18432)
//      red[352*17] f32 (23936) aliases the whole region after compute.
// Total 37376 B -> 4 blocks/CU; grid 1024 blocks fully co-resident.
// ---------------------------------------------------------------------------
#define SB_ROW 72
#define SA_ROW 72

__global__ __launch_bounds__(256, 4) void conv_main(
    const float* __restrict__ image, const float* __restrict__ vectors,
    const float* __restrict__ feat0, const float* __restrict__ feat1,
    const unsigned short* __restrict__ wsT, const float* __restrict__ bcw,
    const float* __restrict__ w_si0, const float* __restrict__ w_si1,
    const float* __restrict__ b_act0, const float* __restrict__ b_act1,
    float* __restrict__ out)
{
  __shared__ __align__(16) char smem[37376];
  unsigned short* sB  = (unsigned short*)smem;            // [128][72] bf16
  float*          sBc = (float*)(smem + 18432);           // [128] f32
  unsigned short* sA  = (unsigned short*)(smem + 18944);  // [128][72] bf16
  float*          red = (float*)smem;                     // [352][17] alias

  const int t    = threadIdx.x;
  const int m    = blockIdx.x >> 8;
  const int a    = blockIdx.x & 255;
  const int w    = t >> 6;
  const int l    = t & 63;
  const int n    = l & 15;        // tile col (tf within tile), also A/B row sel
  const int quad = l >> 4;        // k-group for frags; b-subgroup for C

  // ---- stage WcT (bf16) + bias to LDS ----
  // 128 rows x 64 bf16 = 8192 shorts = 1024 groups of 8 -> 4 iters x 256 thr
  #pragma unroll
  for (int i = 0; i < 4; ++i) {
    int g = t + 256 * i;          // 0..1023 groups of 8 bf16
    int tf = g >> 3, c8 = g & 7;
    *(us8*)&sB[tf * SB_ROW + c8 * 8] = *(const us8*)&wsT[tf * 64 + c8 * 8];
  }
  if (t < 128) sBc[t] = bcw[t];

  // contraction partials
  float p000[2], p110[2], p011[6], p101[6], p111[6];
  #pragma unroll
  for (int i = 0; i < 2; ++i) { p000[i] = 0.f; p110[i] = 0.f; }
  #pragma unroll
  for (int i = 0; i < 6; ++i) { p011[i] = 0.f; p101[i] = 0.f; p111[i] = 0.f; }

  const float* imgMA = image + ((size_t)(m * A_ + a)) * A_ * RBF_;
  const float* vecMA = vectors + ((size_t)(m * A_ + a)) * A_ * 3;

  #pragma unroll 1
  for (int c = 0; c < 2; ++c) {
    if (c) __syncthreads();       // chunk-0 readers done before restage
    // ---- stage image chunk (128 b-rows) as bf16 ----
    const float* base = imgMA + (size_t)c * 128 * RBF_;
    #pragma unroll
    for (int i = 0; i < 4; ++i) {
      int g = t + 256 * i;        // 0..1023 groups of 8 floats
      int r = g >> 3, c8 = g & 7;
      const float* src = base + r * RBF_ + c8 * 8;
      float4 v0 = *(const float4*)(src);
      float4 v1 = *(const float4*)(src + 4);
      us8 pk;
      pk[0] = f2bf(v0.x); pk[1] = f2bf(v0.y); pk[2] = f2bf(v0.z); pk[3] = f2bf(v0.w);
      pk[4] = f2bf(v1.x); pk[5] = f2bf(v1.y); pk[6] = f2bf(v1.z); pk[7] = f2bf(v1.w);
      *(us8*)&sA[r * SA_ROW + c8 * 8] = pk;
    }
    __syncthreads();

    // ---- 2 b-tiles per wave per chunk ----
    #pragma unroll 1
    for (int bti = 0; bti < 2; ++bti) {
      const int btl  = w + 4 * bti;          // 0..7 local b-tile
      const int brow = btl * 16;             // local row base in sA
      const int bg   = c * 128 + brow + quad * 4;  // global b for r=0

      // A-frags for this b-tile (reused across all 8 tf-tiles)
      const bf16x8 a0 = *(const bf16x8*)&sA[(brow + n) * SA_ROW + quad * 8];
      const bf16x8 a1 = *(const bf16x8*)&sA[(brow + n) * SA_ROW + 32 + quad * 8];

      // vectors for this lane's 4 b's
      const float* vp = vecMA + (size_t)bg * 3;
      float vx[4], vy[4], vz[4];
      #pragma unroll
      for (int r = 0; r < 4; ++r) {
        vx[r] = vp[r * 3 + 0]; vy[r] = vp[r * 3 + 1]; vz[r] = vp[r * 3 + 2];
      }

      #pragma unroll
      for (int which = 0; which < 2; ++which) {
        const int f  = which * 16 + n;           // feature within tag
        const int fb = (m * A_ + bg) * F_ + f;   // r advances by F_
        // shared feat loads for the 4 tf-tiles using this feature column
        float ft0[4], g0[4], g1[4], g2[4];
        #pragma unroll
        for (int r = 0; r < 4; ++r) {
          ft0[r] = feat0[fb + r * F_];
          const float* fp = feat1 + (size_t)(fb + r * F_) * 3;
          g0[r] = fp[0]; g1[r] = fp[1]; g2[r] = fp[2];
        }

        #pragma unroll 1
        for (int tag = 0; tag < 4; ++tag) {
          const int ct = tag * 2 + which;        // tf tile index
          const bf16x8 b0 = *(const bf16x8*)&sB[(ct * 16 + n) * SB_ROW + quad * 8];
          const bf16x8 b1 = *(const bf16x8*)&sB[(ct * 16 + n) * SB_ROW + 32 + quad * 8];
          const float bcv = sBc[ct * 16 + n];
          f32x4 acc = {bcv, bcv, bcv, bcv};
          acc = __builtin_amdgcn_mfma_f32_16x16x32_bf16(a0, b0, acc, 0, 0, 0);
          acc = __builtin_amdgcn_mfma_f32_16x16x32_bf16(a1, b1, acc, 0, 0, 0);

          if (tag == 0) {          // 00 -> out_0x0_0
            #pragma unroll
            for (int r = 0; r < 4; ++r)
              p000[which] += acc[r] * ft0[r];
          } else if (tag == 1) {   // 01 -> out_0x1_1 = v * (R*feat0)
            #pragma unroll
            for (int r = 0; r < 4; ++r) {
              float s = acc[r] * ft0[r];
              p011[which * 3 + 0] += vx[r] * s;
              p011[which * 3 + 1] += vy[r] * s;
              p011[which * 3 + 2] += vz[r] * s;
            }
          } else if (tag == 2) {   // 10 -> out_1x0_1 = R * feat1
            #pragma unroll
            for (int r = 0; r < 4; ++r) {
              p101[which * 3 + 0] += acc[r] * g0[r];
              p101[which * 3 + 1] += acc[r] * g1[r];
              p101[which * 3 + 2] += acc[r] * g2[r];
            }
          } else {                 // 11 -> out_1x1_0 (dot), out_1x1_1 (cross)
            #pragma unroll
            for (int r = 0; r < 4; ++r) {
              float Rr = acc[r];
              p110[which] += Rr * (vx[r] * g0[r] + vy[r] * g1[r] + vz[r] * g2[r]);
              p111[which * 3 + 0] += Rr * (vy[r] * g2[r] - vz[r] * g1[r]);
              p111[which * 3 + 1] += Rr * (vz[r] * g0[r] - vx[r] * g2[r]);
              p111[which * 3 + 2] += Rr * (vx[r] * g1[r] - vy[r] * g0[r]);
            }
          }
        }
      }
    }
    __syncthreads();   // all compute on this chunk done (before restage/red)
  }

  // ---- write 16-copy partials (red aliases sB/sBc/sA; all consumed) ----
  const int idx16 = w * 4 + quad;
  // slots: out000: f (0..31) | out110: 32+f | out011: 64+f*3+d
  //        out101: 160+f*3+d | out111: 256+f*3+d       (total 352)
  #pragma unroll
  for (int which = 0; which < 2; ++which) {
    int f = which * 16 + n;
    red[f * 17 + idx16]        = p000[which];
    red[(32 + f) * 17 + idx16] = p110[which];
    #pragma unroll
    for (int d = 0; d < 3; ++d) {
      red[(64 + f * 3 + d) * 17 + idx16]  = p011[which * 3 + d];
      red[(160 + f * 3 + d) * 17 + idx16] = p101[which * 3 + d];
      red[(256 + f * 3 + d) * 17 + idx16] = p111[which * 3 + d];
    }
  }
  __syncthreads();

  // ---- reduce 16 copies; result in column 16 ----
  for (int s = t; s < 352; s += 256) {
    float sm = 0.f;
    #pragma unroll
    for (int j = 0; j < 16; ++j) sm += red[s * 17 + j];
    red[s * 17 + 16] = sm;
  }
  __syncthreads();

  // ---- self-interaction + equivariant activation epilogue ----
  // cat0[i] = red[i*17+16] (i<64: out000|out110)
  // cat1[i] = red[(64+i)*17+16] (i<288: out011|out101|out111, (row,d) packed)
  const int outBase = (m * A_ + a) * SI_;
  if (t < 32) {
    const float* wr = w_si0 + t * 64;
    float s = 0.f;
    #pragma unroll 8
    for (int f = 0; f < 64; ++f) s += red[f * 17 + 16] * wr[f];
    s += b_act0[t];
    out[outBase + t] = sspf(s);
  } else if (t >= 64 && t < 96) {
    int g = t - 64;
    const float* wr = w_si1 + g * 96;
    float s0 = 0.f, s1 = 0.f, s2 = 0.f;
    #pragma unroll 8
    for (int f = 0; f < 96; ++f) {
      float wv = wr[f];
      s0 += red[(64 + f * 3 + 0) * 17 + 16] * wv;
      s1 += red[(64 + f * 3 + 1) * 17 + 16] * wv;
      s2 += red[(64 + f * 3 + 2) * 17 + 16] * wv;
    }
    float n2 = s0 * s0 + s1 * s1 + s2 * s2;
    float n1 = sqrtf(fmaxf(n2, 1e-7f));     // norm_with_epsilon, EPS=1e-7
    float a1 = sspf(n1 + b_act1[g]);
    float sc = a1 / n1;
    int ob = M_ * A_ * SI_ + (outBase + g) * 3;   // o0 is 32768 floats
    out[ob + 0] = s0 * sc;
    out[ob + 1] = s1 * sc;
    out[ob + 2] = s2 * sc;
  }
}

extern "C" void kernel_launch(void* const* d_in, const int* in_sizes, int n_in,
                              void* d_out, int out_size, void* d_ws, size_t ws_size,
                              hipStream_t stream) {
  const float* image   = (const float*)d_in[0];
  const float* vectors = (const float*)d_in[1];
  const float* feat0   = (const float*)d_in[2];
  const float* feat1   = (const float*)d_in[3];
  const float* w_si0   = (const float*)d_in[20];
  const float* w_si1   = (const float*)d_in[21];
  const float* b_act0  = (const float*)d_in[22];
  const float* b_act1  = (const float*)d_in[23];
  unsigned short* wsT = (unsigned short*)d_ws;           // 128*64 bf16 = 16384 B
  float* bcw = (float*)((char*)d_ws + 16384);            // 128 f32
  float* out = (float*)d_out;

  combine_weights<<<32, 256, 0, stream>>>(
      (const float*)d_in[4],  (const float*)d_in[5],
      (const float*)d_in[6],  (const float*)d_in[7],
      (const float*)d_in[8],  (const float*)d_in[9],
      (const float*)d_in[10], (const float*)d_in[11],
      (const float*)d_in[12], (const float*)d_in[13],
      (const float*)d_in[14], (const float*)d_in[15],
      (const float*)d_in[16], (const float*)d_in[17],
      (const float*)d_in[18], (const float*)d_in[19],
      wsT, bcw);

  conv_main<<<M_ * A_, 256, 0, stream>>>(
      image, vectors, feat0, feat1, wsT, bcw,
      w_si0, w_si1, b_act0, b_act1, out);
}